// Round 8
// baseline (646.072 us; speedup 1.0000x reference)
//
#include <hip/hip_runtime.h>
#include <math.h>

#define NN 50000
#define NE 640000
#define H 128
#define EPB 32
#define NPB 32
#define ZB 296        // LDS stride (bf16) for z rows
#define BB 136        // LDS stride (bf16) for 128-wide buffers
#define KP1 288       // padded K for layer 1
#define NZB 264       // LDS stride (bf16) for node 256-wide input
#define SCAN_T 1024
#define CHUNK 49      // ceil(NN / SCAN_T)

typedef __attribute__((ext_vector_type(8))) unsigned short u16x8;
typedef __attribute__((ext_vector_type(8))) __bf16 bf16x8;
typedef __attribute__((ext_vector_type(2))) __bf16 bf16x2;
typedef __attribute__((ext_vector_type(4))) float f32x4;

__device__ __forceinline__ float frcp(float x) {
#if __has_builtin(__builtin_amdgcn_rcpf)
    return __builtin_amdgcn_rcpf(x);
#else
    return 1.0f / x;
#endif
}

__device__ __forceinline__ float silu_f(float v) { return v * frcp(1.0f + __expf(-v)); }
__device__ __forceinline__ float sigmoid_f(float v) { return frcp(1.0f + __expf(-v)); }
__device__ __forceinline__ float tanh_f(float v) { return 1.0f - 2.0f * frcp(1.0f + __expf(2.0f * v)); }

__device__ __forceinline__ unsigned short f2bf(float f) {
    unsigned int u = __builtin_bit_cast(unsigned int, f);
    u += 0x7FFFu + ((u >> 16) & 1u);
    return (unsigned short)(u >> 16);
}

__device__ __forceinline__ float bf2f(unsigned short s) {
    unsigned int u = ((unsigned int)s) << 16;
    return __builtin_bit_cast(float, u);
}

__device__ __forceinline__ unsigned int pkbf(float lo, float hi) {
#if __has_builtin(__builtin_amdgcn_cvt_pk_bf16_f32)
    bf16x2 v = __builtin_amdgcn_cvt_pk_bf16_f32(lo, hi);
    unsigned int r; __builtin_memcpy(&r, &v, 4); return r;
#else
    return (unsigned int)f2bf(lo) | ((unsigned int)f2bf(hi) << 16);
#endif
}

__device__ __forceinline__ f32x4 mfma16(u16x8 a, u16x8 b, f32x4 c) {
    return __builtin_amdgcn_mfma_f32_16x16x32_bf16(
        __builtin_bit_cast(bf16x8, a), __builtin_bit_cast(bf16x8, b), c, 0, 0, 0);
}

template<int KT, int INSTR, bool SYNC_BEFORE_EPI>
__device__ __forceinline__ void layer_mfma(
    const unsigned short* __restrict__ inbuf,
    const unsigned short* __restrict__ wt,
    const float* __restrict__ bias,
    unsigned short* __restrict__ outbuf,
    int wv, int quad, int r16)
{
    f32x4 acc[2][2] = {};
    const int F = wv * 32;
    #pragma unroll
    for (int ks = 0; ks < KT / 32; ks++) {
        int ko = ks * 32 + quad * 8;
        u16x8 b0 = *(const u16x8*)(inbuf + r16 * INSTR + ko);
        u16x8 b1 = *(const u16x8*)(inbuf + (16 + r16) * INSTR + ko);
        u16x8 a0 = *(const u16x8*)(wt + (size_t)(F + r16) * KT + ko);
        u16x8 a1 = *(const u16x8*)(wt + (size_t)(F + 16 + r16) * KT + ko);
        acc[0][0] = mfma16(a0, b0, acc[0][0]);
        acc[0][1] = mfma16(a0, b1, acc[0][1]);
        acc[1][0] = mfma16(a1, b0, acc[1][0]);
        acc[1][1] = mfma16(a1, b1, acc[1][1]);
    }
    if (SYNC_BEFORE_EPI) __syncthreads();
    #pragma unroll
    for (int rt = 0; rt < 2; rt++) {
        int f0 = F + rt * 16 + quad * 4;
        float4 bv = *(const float4*)(bias + f0);
        #pragma unroll
        for (int ci = 0; ci < 2; ci++) {
            int e = ci * 16 + r16;
            float s0 = silu_f(acc[rt][ci][0] + bv.x);
            float s1 = silu_f(acc[rt][ci][1] + bv.y);
            float s2 = silu_f(acc[rt][ci][2] + bv.z);
            float s3 = silu_f(acc[rt][ci][3] + bv.w);
            uint2 p = { pkbf(s0, s1), pkbf(s2, s3) };
            *(uint2*)(outbuf + e * BB + f0) = p;
        }
    }
}

// ---------------- prep kernels ----------------------------------------------
__global__ __launch_bounds__(256) void convert_weights(
    const float* __restrict__ We1, const float* __restrict__ We2,
    const float* __restrict__ Wx1, const float* __restrict__ Wn1,
    const float* __restrict__ Wn2,
    unsigned short* __restrict__ w1t, unsigned short* __restrict__ w2t,
    unsigned short* __restrict__ wx1t, unsigned short* __restrict__ wn1t,
    unsigned short* __restrict__ wn2t)
{
    int i = blockIdx.x * 256 + threadIdx.x;
    const int S1 = 128 * KP1;
    const int S2 = 128 * 128;
    const int S3 = 128 * 256;
    if (i < S1) {
        int n = i / KP1, k = i % KP1;
        w1t[i] = (k < 280) ? f2bf(We1[k * H + n]) : (unsigned short)0;
    } else if (i < S1 + S2) {
        int j = i - S1; int n = j / H, k = j % H;
        w2t[j] = f2bf(We2[k * H + n]);
    } else if (i < S1 + 2 * S2) {
        int j = i - S1 - S2; int n = j / H, k = j % H;
        wx1t[j] = f2bf(Wx1[k * H + n]);
    } else if (i < S1 + 2 * S2 + S3) {
        int j = i - S1 - 2 * S2; int n = j / 256, k = j % 256;
        wn1t[j] = f2bf(Wn1[k * H + n]);
    } else if (i < S1 + 3 * S2 + S3) {
        int j = i - S1 - 2 * S2 - S3; int n = j / H, k = j % H;
        wn2t[j] = f2bf(Wn2[k * H + n]);
    }
}

__global__ __launch_bounds__(256) void hconv_kernel(
    const float* __restrict__ h, unsigned short* __restrict__ h2)
{
    int i = blockIdx.x * 256 + threadIdx.x;   // one per 8 floats
    if (i < NN * H / 8) {
        const float4* p = (const float4*)(h) + i * 2;
        float4 a = p[0], b = p[1];
        uint4 o = { pkbf(a.x, a.y), pkbf(a.z, a.w), pkbf(b.x, b.y), pkbf(b.z, b.w) };
        *(uint4*)(h2 + (size_t)i * 8) = o;
    }
}

__global__ __launch_bounds__(256) void zero_kernel(float4* __restrict__ p, int n4) {
    int i = blockIdx.x * 256 + threadIdx.x;
    if (i < n4) p[i] = make_float4(0.f, 0.f, 0.f, 0.f);
}

__global__ __launch_bounds__(256) void zero_ints(int* __restrict__ p, int n) {
    int i = blockIdx.x * 256 + threadIdx.x;
    if (i < n) p[i] = 0;
}

__global__ __launch_bounds__(256) void hist_kernel(
    const int* __restrict__ ei, int* __restrict__ cnt)
{
    int e = blockIdx.x * 256 + threadIdx.x;
    if (e < NE) atomicAdd(&cnt[ei[NE + e]], 1);
}

__global__ __launch_bounds__(SCAN_T) void scan_kernel(
    int* __restrict__ cnt, int* __restrict__ rowptr)
{
    __shared__ int part[SCAN_T];
    int t = threadIdx.x;
    int beg = t * CHUNK, end = min(beg + CHUNK, NN);
    int s = 0;
    for (int i = beg; i < end; i++) s += cnt[i];
    part[t] = s;
    __syncthreads();
    for (int off = 1; off < SCAN_T; off <<= 1) {
        int v = (t >= off) ? part[t - off] : 0;
        __syncthreads();
        part[t] += v;
        __syncthreads();
    }
    int run = (t == 0) ? 0 : part[t - 1];
    for (int i = beg; i < end; i++) {
        int c = cnt[i];
        rowptr[i] = run;
        cnt[i] = run;     // becomes the scatter cursor
        run += c;
    }
    if (t == 0) rowptr[NN] = NE;
}

__global__ __launch_bounds__(256) void scatter_kernel(
    const int* __restrict__ ei, int* __restrict__ cursor, int* __restrict__ eidx)
{
    int e = blockIdx.x * 256 + threadIdx.x;
    if (e < NE) {
        int d = ei[NE + e];
        int pos = atomicAdd(&cursor[d], 1);
        eidx[pos] = e;
    }
}

// ---------------- CSR-path edge kernel --------------------------------------
__global__ __launch_bounds__(256, 7) void edge_kernel_csr(
    const unsigned short* __restrict__ h2, const float* __restrict__ x,
    const int* __restrict__ ei, const float* __restrict__ edge_attr,
    const unsigned short* __restrict__ w1t, const float* __restrict__ be1,
    const unsigned short* __restrict__ w2t, const float* __restrict__ be2,
    const float* __restrict__ Winf, const float* __restrict__ binf,
    const unsigned short* __restrict__ wx1t, const float* __restrict__ bx1,
    const float* __restrict__ Wx2,
    unsigned short* __restrict__ mijE, float* __restrict__ dx)
{
    __shared__ unsigned short zs[EPB * ZB];
    __shared__ float relx_s[EPB][3];
    __shared__ float eij_s[EPB];
    __shared__ float epart[4][EPB];
    __shared__ float xpart[4][EPB];
    __shared__ int dst_s[EPB];
    __shared__ float winf_s[H];
    __shared__ float wx2_s[H];

    unsigned short* m1 = zs;
    unsigned short* m2 = zs + EPB * BB;

    const int t = threadIdx.x;
    const int e0 = blockIdx.x * EPB;

    if (t >= 128 && t < 256) {
        winf_s[t - 128] = Winf[t - 128];
        wx2_s[t - 128] = Wx2[t - 128];
    }

    // Gather h2[dst] -> z[0:128], h2[src] -> z[128:256]; 8 lanes/edge.
    {
        int e = t >> 3, l = t & 7;
        int s = ei[e0 + e], d = ei[NE + e0 + e];
        const uint4* hd = (const uint4*)(h2 + (size_t)d * H);
        const uint4* hs = (const uint4*)(h2 + (size_t)s * H);
        unsigned short* zr = zs + e * ZB;
        *(uint4*)(zr + l * 16)           = hd[l * 2];
        *(uint4*)(zr + l * 16 + 8)       = hd[l * 2 + 1];
        *(uint4*)(zr + 128 + l * 16)     = hs[l * 2];
        *(uint4*)(zr + 128 + l * 16 + 8) = hs[l * 2 + 1];
    }
    if (t < EPB) {
        int s = ei[e0 + t], d = ei[NE + e0 + t];
        dst_s[t] = d;
        float rx = x[d * 3 + 0] - x[s * 3 + 0];
        float ry = x[d * 3 + 1] - x[s * 3 + 1];
        float rz = x[d * 3 + 2] - x[s * 3 + 2];
        float d2 = rx * rx + ry * ry + rz * rz;
        float dd = sqrtf(d2 + 1e-8f);
        float inv = frcp(dd + 1.0f);
        relx_s[t][0] = rx * inv;
        relx_s[t][1] = ry * inv;
        relx_s[t][2] = rz * inv;
        const float step = 10.0f / 19.0f;
        const float coeff = -0.5f / (step * step);
        unsigned short* zr = zs + t * ZB;
        #pragma unroll
        for (int g = 0; g < 20; g++) {
            float df = dd - step * (float)g;
            zr[256 + g] = f2bf(__expf(coeff * df * df));
        }
        #pragma unroll
        for (int j = 0; j < 4; j++)
            zr[276 + j] = f2bf(edge_attr[(size_t)(e0 + t) * 4 + j]);
        #pragma unroll
        for (int j = 280; j < ZB; j++) zr[j] = 0;
    }
    __syncthreads();

    const int wv = t >> 6, lane = t & 63;
    const int quad = lane >> 4, r16 = lane & 15;
    const int F = wv * 32;

    layer_mfma<KP1, ZB, true>(zs, w1t, be1, m1, wv, quad, r16);
    __syncthreads();

    // Layer 2 + fused eij partial dot
    {
        f32x4 acc[2][2] = {};
        #pragma unroll
        for (int ks = 0; ks < H / 32; ks++) {
            int ko = ks * 32 + quad * 8;
            u16x8 b0 = *(const u16x8*)(m1 + r16 * BB + ko);
            u16x8 b1 = *(const u16x8*)(m1 + (16 + r16) * BB + ko);
            u16x8 a0 = *(const u16x8*)(w2t + (size_t)(F + r16) * H + ko);
            u16x8 a1 = *(const u16x8*)(w2t + (size_t)(F + 16 + r16) * H + ko);
            acc[0][0] = mfma16(a0, b0, acc[0][0]);
            acc[0][1] = mfma16(a0, b1, acc[0][1]);
            acc[1][0] = mfma16(a1, b0, acc[1][0]);
            acc[1][1] = mfma16(a1, b1, acc[1][1]);
        }
        float ep[2] = {0.f, 0.f};
        #pragma unroll
        for (int rt = 0; rt < 2; rt++) {
            int f0 = F + rt * 16 + quad * 4;
            float4 bv = *(const float4*)(be2 + f0);
            float4 wf = *(const float4*)(winf_s + f0);
            #pragma unroll
            for (int ci = 0; ci < 2; ci++) {
                int e = ci * 16 + r16;
                float s0 = silu_f(acc[rt][ci][0] + bv.x);
                float s1 = silu_f(acc[rt][ci][1] + bv.y);
                float s2 = silu_f(acc[rt][ci][2] + bv.z);
                float s3 = silu_f(acc[rt][ci][3] + bv.w);
                ep[ci] += s0 * wf.x + s1 * wf.y + s2 * wf.z + s3 * wf.w;
                uint2 p = { pkbf(s0, s1), pkbf(s2, s3) };
                *(uint2*)(m2 + e * BB + f0) = p;
            }
        }
        #pragma unroll
        for (int ci = 0; ci < 2; ci++) {
            ep[ci] += __shfl_xor(ep[ci], 16, 64);
            ep[ci] += __shfl_xor(ep[ci], 32, 64);
        }
        if (quad == 0) {
            epart[wv][r16] = ep[0];
            epart[wv][16 + r16] = ep[1];
        }
    }
    __syncthreads();

    if (t < EPB) {
        float s = epart[0][t] + epart[1][t] + epart[2][t] + epart[3][t] + binf[0];
        eij_s[t] = sigmoid_f(s);
    }

    // Coord layer, fused with Wx2 dot
    {
        f32x4 acc[2][2] = {};
        #pragma unroll
        for (int ks = 0; ks < H / 32; ks++) {
            int ko = ks * 32 + quad * 8;
            u16x8 b0 = *(const u16x8*)(m2 + r16 * BB + ko);
            u16x8 b1 = *(const u16x8*)(m2 + (16 + r16) * BB + ko);
            u16x8 a0 = *(const u16x8*)(wx1t + (size_t)(F + r16) * H + ko);
            u16x8 a1 = *(const u16x8*)(wx1t + (size_t)(F + 16 + r16) * H + ko);
            acc[0][0] = mfma16(a0, b0, acc[0][0]);
            acc[0][1] = mfma16(a0, b1, acc[0][1]);
            acc[1][0] = mfma16(a1, b0, acc[1][0]);
            acc[1][1] = mfma16(a1, b1, acc[1][1]);
        }
        float xp[2] = {0.f, 0.f};
        #pragma unroll
        for (int rt = 0; rt < 2; rt++) {
            int f0 = F + rt * 16 + quad * 4;
            float4 bv = *(const float4*)(bx1 + f0);
            float4 wf = *(const float4*)(wx2_s + f0);
            #pragma unroll
            for (int ci = 0; ci < 2; ci++) {
                xp[ci] += silu_f(acc[rt][ci][0] + bv.x) * wf.x
                        + silu_f(acc[rt][ci][1] + bv.y) * wf.y
                        + silu_f(acc[rt][ci][2] + bv.z) * wf.z
                        + silu_f(acc[rt][ci][3] + bv.w) * wf.w;
            }
        }
        #pragma unroll
        for (int ci = 0; ci < 2; ci++) {
            xp[ci] += __shfl_xor(xp[ci], 16, 64);
            xp[ci] += __shfl_xor(xp[ci], 32, 64);
        }
        if (quad == 0) {
            xpart[wv][r16] = xp[0];
            xpart[wv][16 + r16] = xp[1];
        }
    }
    __syncthreads();

    // Stream mij*eij as coalesced bf16 rows (no atomics).
    {
        int e = t >> 3, l = t & 7;
        float eij = eij_s[e];
        const unsigned short* row = m2 + e * BB + l * 16;
        u16x8 v0 = *(const u16x8*)(row);
        u16x8 v1 = *(const u16x8*)(row + 8);
        uint4 o0, o1;
        o0.x = pkbf(bf2f(v0[0]) * eij, bf2f(v0[1]) * eij);
        o0.y = pkbf(bf2f(v0[2]) * eij, bf2f(v0[3]) * eij);
        o0.z = pkbf(bf2f(v0[4]) * eij, bf2f(v0[5]) * eij);
        o0.w = pkbf(bf2f(v0[6]) * eij, bf2f(v0[7]) * eij);
        o1.x = pkbf(bf2f(v1[0]) * eij, bf2f(v1[1]) * eij);
        o1.y = pkbf(bf2f(v1[2]) * eij, bf2f(v1[3]) * eij);
        o1.z = pkbf(bf2f(v1[4]) * eij, bf2f(v1[5]) * eij);
        o1.w = pkbf(bf2f(v1[6]) * eij, bf2f(v1[7]) * eij);
        uint4* dst = (uint4*)(mijE + (size_t)(e0 + e) * H + l * 16);
        dst[0] = o0;
        dst[1] = o1;
    }
    // dx atomics: tiny array (600 KB), L2-resident.
    if (t < EPB * 3) {
        int e = t / 3, dim = t % 3;
        float xs = xpart[0][e] + xpart[1][e] + xpart[2][e] + xpart[3][e];
        float xg = tanh_f(xs);
        atomicAdd(&dx[(size_t)dst_s[e] * 3 + dim], relx_s[e][dim] * xg);
    }
}

// ---------------- CSR-path node kernel --------------------------------------
__global__ __launch_bounds__(256, 6) void node_kernel_csr(
    const unsigned short* __restrict__ h2, const float* __restrict__ h,
    const float* __restrict__ x, const float* __restrict__ mask,
    const int* __restrict__ rowptr, const int* __restrict__ eidx,
    const unsigned short* __restrict__ mijE,
    const unsigned short* __restrict__ wn1t, const float* __restrict__ bn1,
    const unsigned short* __restrict__ wn2t, const float* __restrict__ bn2,
    float* __restrict__ hout, float* __restrict__ dx_xout)
{
    __shared__ unsigned short nzs[NPB * NZB];
    unsigned short* nbuf = nzs;

    const int t = threadIdx.x;
    const int n0 = blockIdx.x * NPB;

    // mi gather-sum in fp32 registers, then bf16 -> nzs; h2 copied as-is.
    {
        int r = t >> 3, l = t & 7;
        int n = n0 + r;
        float av[16];
        #pragma unroll
        for (int k = 0; k < 16; k++) av[k] = 0.f;
        if (n < NN) {
            int beg = rowptr[n], end = rowptr[n + 1];
            for (int j = beg; j < end; j++) {
                int e = eidx[j];
                const u16x8* p = (const u16x8*)(mijE + (size_t)e * H + l * 16);
                u16x8 a = p[0], b = p[1];
                #pragma unroll
                for (int k = 0; k < 8; k++) {
                    av[k]     += bf2f(a[k]);
                    av[8 + k] += bf2f(b[k]);
                }
            }
        }
        unsigned short* zr = nzs + r * NZB;
        uint4 pa = { pkbf(av[0], av[1]), pkbf(av[2], av[3]),
                     pkbf(av[4], av[5]), pkbf(av[6], av[7]) };
        uint4 pb = { pkbf(av[8], av[9]), pkbf(av[10], av[11]),
                     pkbf(av[12], av[13]), pkbf(av[14], av[15]) };
        *(uint4*)(zr + l * 16)     = pa;
        *(uint4*)(zr + l * 16 + 8) = pb;
        if (n < NN) {
            const uint4* hp = (const uint4*)(h2 + (size_t)n * H);
            *(uint4*)(zr + 128 + l * 16)     = hp[l * 2];
            *(uint4*)(zr + 128 + l * 16 + 8) = hp[l * 2 + 1];
        } else {
            uint4 zf = {0u, 0u, 0u, 0u};
            *(uint4*)(zr + 128 + l * 16)     = zf;
            *(uint4*)(zr + 128 + l * 16 + 8) = zf;
        }
    }

    float xo = 0.f;
    int xn = -1, xdim = 0;
    if (t < NPB * 3) {
        int r = t / 3; xdim = t % 3;
        int n = n0 + r;
        if (n < NN) {
            xn = n;
            xo = x[(size_t)n * 3 + xdim] + dx_xout[(size_t)n * 3 + xdim] * mask[n];
        }
    }
    __syncthreads();

    if (xn >= 0) dx_xout[(size_t)xn * 3 + xdim] = xo;

    const int wv = t >> 6, lane = t & 63;
    const int quad = lane >> 4, r16 = lane & 15;

    layer_mfma<2 * H, NZB, true>(nzs, wn1t, bn1, nbuf, wv, quad, r16);
    __syncthreads();

    {
        f32x4 acc[2][2] = {};
        const int F = wv * 32;
        #pragma unroll
        for (int ks = 0; ks < H / 32; ks++) {
            int ko = ks * 32 + quad * 8;
            u16x8 b0 = *(const u16x8*)(nbuf + r16 * BB + ko);
            u16x8 b1 = *(const u16x8*)(nbuf + (16 + r16) * BB + ko);
            u16x8 a0 = *(const u16x8*)(wn2t + (size_t)(F + r16) * H + ko);
            u16x8 a1 = *(const u16x8*)(wn2t + (size_t)(F + 16 + r16) * H + ko);
            acc[0][0] = mfma16(a0, b0, acc[0][0]);
            acc[0][1] = mfma16(a0, b1, acc[0][1]);
            acc[1][0] = mfma16(a1, b0, acc[1][0]);
            acc[1][1] = mfma16(a1, b1, acc[1][1]);
        }
        #pragma unroll
        for (int rt = 0; rt < 2; rt++) {
            int f0 = F + rt * 16 + quad * 4;
            float4 bv = *(const float4*)(bn2 + f0);
            #pragma unroll
            for (int ci = 0; ci < 2; ci++) {
                int n = n0 + ci * 16 + r16;
                if (n < NN) {
                    float4 hv = *(const float4*)(h + (size_t)n * H + f0);
                    float4 o;
                    o.x = hv.x + acc[rt][ci][0] + bv.x;
                    o.y = hv.y + acc[rt][ci][1] + bv.y;
                    o.z = hv.z + acc[rt][ci][2] + bv.z;
                    o.w = hv.w + acc[rt][ci][3] + bv.w;
                    *(float4*)(hout + (size_t)n * H + f0) = o;
                }
            }
        }
    }
}

// ---------------- fallback (R7) kernels -------------------------------------
__global__ __launch_bounds__(256, 7) void edge_kernel_atomic(
    const float* __restrict__ h, const float* __restrict__ x,
    const int* __restrict__ ei, const float* __restrict__ edge_attr,
    const unsigned short* __restrict__ w1t, const float* __restrict__ be1,
    const unsigned short* __restrict__ w2t, const float* __restrict__ be2,
    const float* __restrict__ Winf, const float* __restrict__ binf,
    const unsigned short* __restrict__ wx1t, const float* __restrict__ bx1,
    const float* __restrict__ Wx2,
    float* __restrict__ mi, float* __restrict__ dx)
{
    __shared__ unsigned short zs[EPB * ZB];
    __shared__ float relx_s[EPB][3];
    __shared__ float eij_s[EPB];
    __shared__ float epart[4][EPB];
    __shared__ float xpart[4][EPB];
    __shared__ int dst_s[EPB];
    __shared__ float winf_s[H];
    __shared__ float wx2_s[H];

    unsigned short* m1 = zs;
    unsigned short* m2 = zs + EPB * BB;

    const int t = threadIdx.x;
    const int e0 = blockIdx.x * EPB;

    if (t >= 128 && t < 256) {
        winf_s[t - 128] = Winf[t - 128];
        wx2_s[t - 128] = Wx2[t - 128];
    }
    {
        int e = t >> 3, l = t & 7;
        int s = ei[e0 + e], d = ei[NE + e0 + e];
        const float4* hd = (const float4*)(h + (size_t)d * H);
        const float4* hs = (const float4*)(h + (size_t)s * H);
        unsigned short* zr = zs + e * ZB;
        float4 v0 = hd[l * 4 + 0], v1 = hd[l * 4 + 1];
        float4 v2 = hd[l * 4 + 2], v3 = hd[l * 4 + 3];
        uint4 p0 = { pkbf(v0.x, v0.y), pkbf(v0.z, v0.w), pkbf(v1.x, v1.y), pkbf(v1.z, v1.w) };
        uint4 p1 = { pkbf(v2.x, v2.y), pkbf(v2.z, v2.w), pkbf(v3.x, v3.y), pkbf(v3.z, v3.w) };
        *(uint4*)(zr + l * 16) = p0;
        *(uint4*)(zr + l * 16 + 8) = p1;
        float4 w0 = hs[l * 4 + 0], w1 = hs[l * 4 + 1];
        float4 w2 = hs[l * 4 + 2], w3 = hs[l * 4 + 3];
        uint4 q0 = { pkbf(w0.x, w0.y), pkbf(w0.z, w0.w), pkbf(w1.x, w1.y), pkbf(w1.z, w1.w) };
        uint4 q1 = { pkbf(w2.x, w2.y), pkbf(w2.z, w2.w), pkbf(w3.x, w3.y), pkbf(w3.z, w3.w) };
        *(uint4*)(zr + 128 + l * 16) = q0;
        *(uint4*)(zr + 128 + l * 16 + 8) = q1;
    }
    if (t < EPB) {
        int s = ei[e0 + t], d = ei[NE + e0 + t];
        dst_s[t] = d;
        float rx = x[d * 3 + 0] - x[s * 3 + 0];
        float ry = x[d * 3 + 1] - x[s * 3 + 1];
        float rz = x[d * 3 + 2] - x[s * 3 + 2];
        float d2 = rx * rx + ry * ry + rz * rz;
        float dd = sqrtf(d2 + 1e-8f);
        float inv = frcp(dd + 1.0f);
        relx_s[t][0] = rx * inv;
        relx_s[t][1] = ry * inv;
        relx_s[t][2] = rz * inv;
        const float step = 10.0f / 19.0f;
        const float coeff = -0.5f / (step * step);
        unsigned short* zr = zs + t * ZB;
        #pragma unroll
        for (int g = 0; g < 20; g++) {
            float df = dd - step * (float)g;
            zr[256 + g] = f2bf(__expf(coeff * df * df));
        }
        #pragma unroll
        for (int j = 0; j < 4; j++)
            zr[276 + j] = f2bf(edge_attr[(size_t)(e0 + t) * 4 + j]);
        #pragma unroll
        for (int j = 280; j < ZB; j++) zr[j] = 0;
    }
    __syncthreads();

    const int wv = t >> 6, lane = t & 63;
    const int quad = lane >> 4, r16 = lane & 15;
    const int F = wv * 32;

    layer_mfma<KP1, ZB, true>(zs, w1t, be1, m1, wv, quad, r16);
    __syncthreads();

    {
        f32x4 acc[2][2] = {};
        #pragma unroll
        for (int ks = 0; ks < H / 32; ks++) {
            int ko = ks * 32 + quad * 8;
            u16x8 b0 = *(const u16x8*)(m1 + r16 * BB + ko);
            u16x8 b1 = *(const u16x8*)(m1 + (16 + r16) * BB + ko);
            u16x8 a0 = *(const u16x8*)(w2t + (size_t)(F + r16) * H + ko);
            u16x8 a1 = *(const u16x8*)(w2t + (size_t)(F + 16 + r16) * H + ko);
            acc[0][0] = mfma16(a0, b0, acc[0][0]);
            acc[0][1] = mfma16(a0, b1, acc[0][1]);
            acc[1][0] = mfma16(a1, b0, acc[1][0]);
            acc[1][1] = mfma16(a1, b1, acc[1][1]);
        }
        float ep[2] = {0.f, 0.f};
        #pragma unroll
        for (int rt = 0; rt < 2; rt++) {
            int f0 = F + rt * 16 + quad * 4;
            float4 bv = *(const float4*)(be2 + f0);
            float4 wf = *(const float4*)(winf_s + f0);
            #pragma unroll
            for (int ci = 0; ci < 2; ci++) {
                int e = ci * 16 + r16;
                float s0 = silu_f(acc[rt][ci][0] + bv.x);
                float s1 = silu_f(acc[rt][ci][1] + bv.y);
                float s2 = silu_f(acc[rt][ci][2] + bv.z);
                float s3 = silu_f(acc[rt][ci][3] + bv.w);
                ep[ci] += s0 * wf.x + s1 * wf.y + s2 * wf.z + s3 * wf.w;
                uint2 p = { pkbf(s0, s1), pkbf(s2, s3) };
                *(uint2*)(m2 + e * BB + f0) = p;
            }
        }
        #pragma unroll
        for (int ci = 0; ci < 2; ci++) {
            ep[ci] += __shfl_xor(ep[ci], 16, 64);
            ep[ci] += __shfl_xor(ep[ci], 32, 64);
        }
        if (quad == 0) {
            epart[wv][r16] = ep[0];
            epart[wv][16 + r16] = ep[1];
        }
    }
    __syncthreads();

    if (t < EPB) {
        float s = epart[0][t] + epart[1][t] + epart[2][t] + epart[3][t] + binf[0];
        eij_s[t] = sigmoid_f(s);
    }
    {
        f32x4 acc[2][2] = {};
        #pragma unroll
        for (int ks = 0; ks < H / 32; ks++) {
            int ko = ks * 32 + quad * 8;
            u16x8 b0 = *(const u16x8*)(m2 + r16 * BB + ko);
            u16x8 b1 = *(const u16x8*)(m2 + (16 + r16) * BB + ko);
            u16x8 a0 = *(const u16x8*)(wx1t + (size_t)(F + r16) * H + ko);
            u16x8 a1 = *(const u16x8*)(wx1t + (size_t)(F + 16 + r16) * H + ko);
            acc[0][0] = mfma16(a0, b0, acc[0][0]);
            acc[0][1] = mfma16(a0, b1, acc[0][1]);
            acc[1][0] = mfma16(a1, b0, acc[1][0]);
            acc[1][1] = mfma16(a1, b1, acc[1][1]);
        }
        float xp[2] = {0.f, 0.f};
        #pragma unroll
        for (int rt = 0; rt < 2; rt++) {
            int f0 = F + rt * 16 + quad * 4;
            float4 bv = *(const float4*)(bx1 + f0);
            float4 wf = *(const float4*)(wx2_s + f0);
            #pragma unroll
            for (int ci = 0; ci < 2; ci++) {
                xp[ci] += silu_f(acc[rt][ci][0] + bv.x) * wf.x
                        + silu_f(acc[rt][ci][1] + bv.y) * wf.y
                        + silu_f(acc[rt][ci][2] + bv.z) * wf.z
                        + silu_f(acc[rt][ci][3] + bv.w) * wf.w;
            }
        }
        #pragma unroll
        for (int ci = 0; ci < 2; ci++) {
            xp[ci] += __shfl_xor(xp[ci], 16, 64);
            xp[ci] += __shfl_xor(xp[ci], 32, 64);
        }
        if (quad == 0) {
            xpart[wv][r16] = xp[0];
            xpart[wv][16 + r16] = xp[1];
        }
    }
    __syncthreads();

    {
        int k = t & 127, eh = t >> 7;
        for (int e = eh; e < EPB; e += 2) {
            float mv = bf2f(m2[e * BB + k]) * eij_s[e];
            atomicAdd(&mi[(size_t)dst_s[e] * H + k], mv);
        }
        if (t < EPB * 3) {
            int e = t / 3, dim = t % 3;
            float xs = xpart[0][e] + xpart[1][e] + xpart[2][e] + xpart[3][e];
            float xg = tanh_f(xs);
            atomicAdd(&dx[(size_t)dst_s[e] * 3 + dim], relx_s[e][dim] * xg);
        }
    }
}

__global__ __launch_bounds__(256, 8) void node_kernel_atomic(
    const float* __restrict__ h, const float* __restrict__ x,
    const float* __restrict__ mask,
    const unsigned short* __restrict__ wn1t, const float* __restrict__ bn1,
    const unsigned short* __restrict__ wn2t, const float* __restrict__ bn2,
    float* __restrict__ mi_hout, float* __restrict__ dx_xout)
{
    __shared__ unsigned short nzs[NPB * NZB];
    unsigned short* nbuf = nzs;

    const int t = threadIdx.x;
    const int n0 = blockIdx.x * NPB;

    {
        int r = t >> 3, l = t & 7;
        int n = n0 + r;
        unsigned short* zr = nzs + r * NZB;
        if (n < NN) {
            const float4* mi4 = (const float4*)(mi_hout + (size_t)n * H);
            const float4* h4  = (const float4*)(h + (size_t)n * H);
            float4 v0 = mi4[l * 4 + 0], v1 = mi4[l * 4 + 1];
            float4 v2 = mi4[l * 4 + 2], v3 = mi4[l * 4 + 3];
            uint4 p0 = { pkbf(v0.x, v0.y), pkbf(v0.z, v0.w), pkbf(v1.x, v1.y), pkbf(v1.z, v1.w) };
            uint4 p1 = { pkbf(v2.x, v2.y), pkbf(v2.z, v2.w), pkbf(v3.x, v3.y), pkbf(v3.z, v3.w) };
            *(uint4*)(zr + l * 16) = p0;
            *(uint4*)(zr + l * 16 + 8) = p1;
            float4 w0 = h4[l * 4 + 0], w1 = h4[l * 4 + 1];
            float4 w2 = h4[l * 4 + 2], w3 = h4[l * 4 + 3];
            uint4 q0 = { pkbf(w0.x, w0.y), pkbf(w0.z, w0.w), pkbf(w1.x, w1.y), pkbf(w1.z, w1.w) };
            uint4 q1 = { pkbf(w2.x, w2.y), pkbf(w2.z, w2.w), pkbf(w3.x, w3.y), pkbf(w3.z, w3.w) };
            *(uint4*)(zr + 128 + l * 16) = q0;
            *(uint4*)(zr + 128 + l * 16 + 8) = q1;
        } else {
            uint4 zf = {0u, 0u, 0u, 0u};
            *(uint4*)(zr + l * 16) = zf;
            *(uint4*)(zr + l * 16 + 8) = zf;
            *(uint4*)(zr + 128 + l * 16) = zf;
            *(uint4*)(zr + 128 + l * 16 + 8) = zf;
        }
    }

    float xo = 0.f;
    int xn = -1, xdim = 0;
    if (t < NPB * 3) {
        int r = t / 3; xdim = t % 3;
        int n = n0 + r;
        if (n < NN) {
            xn = n;
            xo = x[(size_t)n * 3 + xdim] + dx_xout[(size_t)n * 3 + xdim] * mask[n];
        }
    }
    __syncthreads();

    if (xn >= 0) dx_xout[(size_t)xn * 3 + xdim] = xo;

    const int wv = t >> 6, lane = t & 63;
    const int quad = lane >> 4, r16 = lane & 15;

    layer_mfma<2 * H, NZB, true>(nzs, wn1t, bn1, nbuf, wv, quad, r16);
    __syncthreads();

    {
        f32x4 acc[2][2] = {};
        const int F = wv * 32;
        #pragma unroll
        for (int ks = 0; ks < H / 32; ks++) {
            int ko = ks * 32 + quad * 8;
            u16x8 b0 = *(const u16x8*)(nbuf + r16 * BB + ko);
            u16x8 b1 = *(const u16x8*)(nbuf + (16 + r16) * BB + ko);
            u16x8 a0 = *(const u16x8*)(wn2t + (size_t)(F + r16) * H + ko);
            u16x8 a1 = *(const u16x8*)(wn2t + (size_t)(F + 16 + r16) * H + ko);
            acc[0][0] = mfma16(a0, b0, acc[0][0]);
            acc[0][1] = mfma16(a0, b1, acc[0][1]);
            acc[1][0] = mfma16(a1, b0, acc[1][0]);
            acc[1][1] = mfma16(a1, b1, acc[1][1]);
        }
        #pragma unroll
        for (int rt = 0; rt < 2; rt++) {
            int f0 = F + rt * 16 + quad * 4;
            float4 bv = *(const float4*)(bn2 + f0);
            #pragma unroll
            for (int ci = 0; ci < 2; ci++) {
                int n = n0 + ci * 16 + r16;
                if (n < NN) {
                    float4 hv = *(const float4*)(h + (size_t)n * H + f0);
                    float4 o;
                    o.x = hv.x + acc[rt][ci][0] + bv.x;
                    o.y = hv.y + acc[rt][ci][1] + bv.y;
                    o.z = hv.z + acc[rt][ci][2] + bv.z;
                    o.w = hv.w + acc[rt][ci][3] + bv.w;
                    *(float4*)(mi_hout + (size_t)n * H + f0) = o;
                }
            }
        }
    }
}

extern "C" void kernel_launch(void* const* d_in, const int* in_sizes, int n_in,
                              void* d_out, int out_size, void* d_ws, size_t ws_size,
                              hipStream_t stream) {
    const float* h     = (const float*)d_in[0];
    const float* x     = (const float*)d_in[1];
    const int*   ei    = (const int*)d_in[2];
    const float* mask  = (const float*)d_in[3];
    const float* eattr = (const float*)d_in[4];
    const float* We1   = (const float*)d_in[5];
    const float* be1   = (const float*)d_in[6];
    const float* We2   = (const float*)d_in[7];
    const float* be2   = (const float*)d_in[8];
    const float* Winf  = (const float*)d_in[9];
    const float* binf  = (const float*)d_in[10];
    const float* Wx1   = (const float*)d_in[11];
    const float* bx1   = (const float*)d_in[12];
    const float* Wx2   = (const float*)d_in[13];
    const float* Wn1   = (const float*)d_in[14];
    const float* bn1   = (const float*)d_in[15];
    const float* Wn2   = (const float*)d_in[16];
    const float* bn2   = (const float*)d_in[17];

    float* hout = (float*)d_out;                  // also mi accumulator in fallback
    float* dx   = hout + (size_t)NN * H;

    // ---- workspace layout ----
    const size_t W_SH = 128 * KP1 + 3 * 128 * H + 128 * 256;   // weight shorts
    unsigned short* w1t  = (unsigned short*)d_ws;
    unsigned short* w2t  = w1t + 128 * KP1;
    unsigned short* wx1t = w2t + 128 * H;
    unsigned short* wn1t = wx1t + 128 * H;
    unsigned short* wn2t = wn1t + 128 * 256;
    unsigned short* h2   = wn2t + 128 * H;                     // NN*H shorts
    int* cnt    = (int*)(h2 + (size_t)NN * H);                 // NN (also cursor)
    int* rowptr = cnt + NN;                                    // NN+1
    int* eidx   = rowptr + NN + 1;                             // NE
    unsigned short* mijE = (unsigned short*)(eidx + NE);       // NE*H shorts
    size_t need = (char*)(mijE + (size_t)NE * H) - (char*)d_ws;
    const bool use_csr = ws_size >= need;

    const int wconv_total = (int)W_SH;
    convert_weights<<<(wconv_total + 255) / 256, 256, 0, stream>>>(
        We1, We2, Wx1, Wn1, Wn2, w1t, w2t, wx1t, wn1t, wn2t);

    if (use_csr) {
        hconv_kernel<<<(NN * H / 8 + 255) / 256, 256, 0, stream>>>(h, h2);
        zero_ints<<<(NN + 255) / 256, 256, 0, stream>>>(cnt, NN);
        zero_kernel<<<(NN * 3 / 4 + 255) / 256, 256, 0, stream>>>((float4*)dx, NN * 3 / 4);
        hist_kernel<<<(NE + 255) / 256, 256, 0, stream>>>(ei, cnt);
        scan_kernel<<<1, SCAN_T, 0, stream>>>(cnt, rowptr);
        scatter_kernel<<<(NE + 255) / 256, 256, 0, stream>>>(ei, cnt, eidx);

        edge_kernel_csr<<<NE / EPB, 256, 0, stream>>>(
            h2, x, ei, eattr, w1t, be1, w2t, be2, Winf, binf, wx1t, bx1, Wx2,
            mijE, dx);

        node_kernel_csr<<<(NN + NPB - 1) / NPB, 256, 0, stream>>>(
            h2, h, x, mask, rowptr, eidx, mijE, wn1t, bn1, wn2t, bn2, hout, dx);
    } else {
        const int total4 = (NN * H + NN * 3) / 4;
        zero_kernel<<<(total4 + 255) / 256, 256, 0, stream>>>((float4*)d_out, total4);

        edge_kernel_atomic<<<NE / EPB, 256, 0, stream>>>(
            h, x, ei, eattr, w1t, be1, w2t, be2, Winf, binf, wx1t, bx1, Wx2,
            hout, dx);

        node_kernel_atomic<<<(NN + NPB - 1) / NPB, 256, 0, stream>>>(
            h, x, mask, wn1t, bn1, wn2t, bn2, hout, dx);
    }
}